// Round 1
// baseline (1502.997 us; speedup 1.0000x reference)
//
#include <hip/hip_runtime.h>

// GraphSAGE 2-layer forward on MI355X.
// Layout of d_ws (floats): [deg N][inv_deg N][agg3 3N][agg128 128N]  ~= 53 MB

__global__ void k_edge_pass1(const int* __restrict__ src, const int* __restrict__ dst,
                             const float* __restrict__ x, float* __restrict__ deg,
                             float* __restrict__ agg3, int E) {
    int e = blockIdx.x * blockDim.x + threadIdx.x;
    if (e >= E) return;
    int s = src[e], d = dst[e];
    atomicAdd(&deg[d], 1.0f);
    atomicAdd(&agg3[d * 3 + 0], x[s * 3 + 0]);
    atomicAdd(&agg3[d * 3 + 1], x[s * 3 + 1]);
    atomicAdd(&agg3[d * 3 + 2], x[s * 3 + 2]);
}

__global__ void k_inv(const float* __restrict__ deg, float* __restrict__ inv_deg, int N) {
    int i = blockIdx.x * blockDim.x + threadIdx.x;
    if (i < N) inv_deg[i] = 1.0f / fmaxf(deg[i], 1.0f);
}

// One block (128 threads) per node: linear (K=3) + ReLU + LayerNorm(128).
__global__ void k_l0_ln(const float* __restrict__ x, const float* __restrict__ agg3,
                        const float* __restrict__ inv_deg,
                        const float* __restrict__ Wl0, const float* __restrict__ Wr0,
                        const float* __restrict__ b0,
                        const float* __restrict__ ln_g, const float* __restrict__ ln_b,
                        float* __restrict__ h_out) {
    const int node = blockIdx.x;
    const int j = threadIdx.x;
    const float inv = inv_deg[node];
    const float a0 = agg3[node * 3 + 0] * inv;
    const float a1 = agg3[node * 3 + 1] * inv;
    const float a2 = agg3[node * 3 + 2] * inv;
    const float x0 = x[node * 3 + 0], x1 = x[node * 3 + 1], x2 = x[node * 3 + 2];

    float acc = b0[j];
    acc += a0 * Wl0[0 * 128 + j] + a1 * Wl0[1 * 128 + j] + a2 * Wl0[2 * 128 + j];
    acc += x0 * Wr0[0 * 128 + j] + x1 * Wr0[1 * 128 + j] + x2 * Wr0[2 * 128 + j];
    float v = fmaxf(acc, 0.0f);

    // LayerNorm over the 128-wide block: wave(64)-reduce then combine 2 waves.
    float s = v, q = v * v;
#pragma unroll
    for (int off = 32; off >= 1; off >>= 1) {
        s += __shfl_down(s, off, 64);
        q += __shfl_down(q, off, 64);
    }
    __shared__ float ls[2], lq[2];
    __shared__ float smu, srs;
    const int wid = j >> 6, lane = j & 63;
    if (lane == 0) { ls[wid] = s; lq[wid] = q; }
    __syncthreads();
    if (j == 0) {
        float S = ls[0] + ls[1], Q = lq[0] + lq[1];
        float mu = S * (1.0f / 128.0f);
        float var = Q * (1.0f / 128.0f) - mu * mu;
        smu = mu;
        srs = rsqrtf(var + 1e-5f);
    }
    __syncthreads();
    h_out[(size_t)node * 128 + j] = (v - smu) * srs * ln_g[j] + ln_b[j];
}

// Two edges per 256-thread block; thread handles one of 128 feature lanes.
__global__ void k_edge_pass2(const int* __restrict__ src, const int* __restrict__ dst,
                             const float* __restrict__ h, float* __restrict__ agg, int E) {
    int e = blockIdx.x * 2 + (threadIdx.x >> 7);
    int j = threadIdx.x & 127;
    if (e >= E) return;
    int s = src[e], d = dst[e];
    atomicAdd(&agg[(size_t)d * 128 + j], h[(size_t)s * 128 + j]);
}

// One block (128 threads) per node: out = relu(agg*inv @ Wl1 + h @ Wr1 + b1).
// h and out alias (both d_out): row is staged into LDS before overwrite.
__global__ void k_l1(float* hout, const float* __restrict__ agg,
                     const float* __restrict__ inv_deg,
                     const float* __restrict__ Wl1, const float* __restrict__ Wr1,
                     const float* __restrict__ b1) {
    const int node = blockIdx.x;
    const int j = threadIdx.x;
    __shared__ float sa[128], sh[128];
    const float inv = inv_deg[node];
    sa[j] = agg[(size_t)node * 128 + j] * inv;
    sh[j] = hout[(size_t)node * 128 + j];
    __syncthreads();
    float acc = b1[j];
#pragma unroll 8
    for (int k = 0; k < 128; k++) {
        acc += sa[k] * Wl1[k * 128 + j] + sh[k] * Wr1[k * 128 + j];
    }
    hout[(size_t)node * 128 + j] = fmaxf(acc, 0.0f);
}

extern "C" void kernel_launch(void* const* d_in, const int* in_sizes, int n_in,
                              void* d_out, int out_size, void* d_ws, size_t ws_size,
                              hipStream_t stream) {
    const float* x    = (const float*)d_in[0];
    const int*   ei   = (const int*)d_in[1];
    const float* Wl0  = (const float*)d_in[2];
    const float* Wr0  = (const float*)d_in[3];
    const float* b0   = (const float*)d_in[4];
    const float* Wl1  = (const float*)d_in[5];
    const float* Wr1  = (const float*)d_in[6];
    const float* b1   = (const float*)d_in[7];
    const float* ln_g = (const float*)d_in[8];
    const float* ln_b = (const float*)d_in[9];
    float* out = (float*)d_out;

    const int N = in_sizes[0] / 3;
    const int E = in_sizes[1] / 2;
    const int* src = ei;
    const int* dst = ei + E;

    float* ws      = (float*)d_ws;
    float* deg     = ws;
    float* inv_deg = ws + (size_t)N;
    float* agg3    = ws + 2 * (size_t)N;
    float* agg128  = ws + 5 * (size_t)N;

    // zero deg + inv_deg + agg3 + agg128 in one shot (stream-ordered, capturable)
    hipMemsetAsync(d_ws, 0, (size_t)(5 + 128) * N * sizeof(float), stream);

    k_edge_pass1<<<(E + 255) / 256, 256, 0, stream>>>(src, dst, x, deg, agg3, E);
    k_inv<<<(N + 255) / 256, 256, 0, stream>>>(deg, inv_deg, N);
    k_l0_ln<<<N, 128, 0, stream>>>(x, agg3, inv_deg, Wl0, Wr0, b0, ln_g, ln_b, out);
    k_edge_pass2<<<(E + 1) / 2, 256, 0, stream>>>(src, dst, out, agg128, E);
    k_l1<<<N, 128, 0, stream>>>(out, agg128, inv_deg, Wl1, Wr1, b1);
}

// Round 2
// 636.316 us; speedup vs baseline: 2.3620x; 2.3620x over previous
//
#include <hip/hip_runtime.h>

// GraphSAGE 2-layer forward, CSR-gather formulation (no wide-row atomics).
// ws layout (ints): [counts N][cursor N][row_start N][blk_sums 128][sorted_src E][h_bf16 64N words]

#define NT 16  // nodes per block in fused layer-1

__device__ __forceinline__ unsigned bf16_rne(float f) {
    unsigned u = __float_as_uint(f);
    return (u + 0x7FFFu + ((u >> 16) & 1u)) >> 16;
}

__global__ void k_hist(const int* __restrict__ dst, int* __restrict__ counts, int E) {
    int e = blockIdx.x * blockDim.x + threadIdx.x;
    if (e < E) atomicAdd(&counts[dst[e]], 1);
}

// Block-level scan: 256 threads x 4 items = 1024/block.
__global__ void k_scan_blk(const int* __restrict__ counts, int* __restrict__ row_start,
                           int* __restrict__ blk_sums, int N) {
    __shared__ int lds[256];
    int t = threadIdx.x;
    int base = blockIdx.x * 1024 + t * 4;
    int c0 = 0, c1 = 0, c2 = 0, c3 = 0;
    if (base + 0 < N) c0 = counts[base + 0];
    if (base + 1 < N) c1 = counts[base + 1];
    if (base + 2 < N) c2 = counts[base + 2];
    if (base + 3 < N) c3 = counts[base + 3];
    int s = c0 + c1 + c2 + c3;
    lds[t] = s;
    __syncthreads();
    for (int off = 1; off < 256; off <<= 1) {
        int v = (t >= off) ? lds[t - off] : 0;
        __syncthreads();
        lds[t] += v;
        __syncthreads();
    }
    int excl = lds[t] - s;
    if (base + 0 < N) row_start[base + 0] = excl;
    if (base + 1 < N) row_start[base + 1] = excl + c0;
    if (base + 2 < N) row_start[base + 2] = excl + c0 + c1;
    if (base + 3 < N) row_start[base + 3] = excl + c0 + c1 + c2;
    if (t == 255) blk_sums[blockIdx.x] = lds[255];
}

__global__ void k_scan_top(int* __restrict__ blk_sums, int nblk) {
    if (threadIdx.x == 0) {
        int run = 0;
        for (int b = 0; b < nblk; b++) { int v = blk_sums[b]; blk_sums[b] = run; run += v; }
    }
}

__global__ void k_scan_add(int* __restrict__ row_start, const int* __restrict__ blk_sums, int N) {
    int off = blk_sums[blockIdx.x];
    int base = blockIdx.x * 1024 + threadIdx.x * 4;
#pragma unroll
    for (int i = 0; i < 4; i++)
        if (base + i < N) row_start[base + i] += off;
}

__global__ void k_scatter(const int* __restrict__ src, const int* __restrict__ dst,
                          const int* __restrict__ row_start, int* __restrict__ cursor,
                          int* __restrict__ sorted_src, int E) {
    int e = blockIdx.x * blockDim.x + threadIdx.x;
    if (e >= E) return;
    int s = src[e], d = dst[e];
    int pos = atomicAdd(&cursor[d], 1);
    sorted_src[row_start[d] + pos] = s;
}

// Layer 0 fused: CSR mean-aggregate of x (D=3) + linear(6->128) + ReLU + LayerNorm.
// One wave per node (lane handles features 2*lane, 2*lane+1). Writes fp32 h (d_out)
// and a bf16 copy for neighbor gathering in layer 1.
__global__ __launch_bounds__(256) void k_l0(
        const float* __restrict__ x, const int* __restrict__ counts,
        const int* __restrict__ row_start, const int* __restrict__ sorted_src,
        const float* __restrict__ Wl0, const float* __restrict__ Wr0,
        const float* __restrict__ b0,
        const float* __restrict__ ln_g, const float* __restrict__ ln_b,
        float* __restrict__ out, unsigned* __restrict__ h_bf, int N) {
    int wid = threadIdx.x >> 6, lane = threadIdx.x & 63;
    int node = blockIdx.x * 4 + wid;
    if (node >= N) return;
    int deg = counts[node], rs = row_start[node];
    float inv = 1.0f / fmaxf((float)deg, 1.0f);
    float a0 = 0, a1 = 0, a2 = 0;
    for (int k = lane; k < deg; k += 64) {
        int s = sorted_src[rs + k];
        a0 += x[3 * s + 0];
        a1 += x[3 * s + 1];
        a2 += x[3 * s + 2];
    }
#pragma unroll
    for (int off = 32; off; off >>= 1) {
        a0 += __shfl_xor(a0, off, 64);
        a1 += __shfl_xor(a1, off, 64);
        a2 += __shfl_xor(a2, off, 64);
    }
    a0 *= inv; a1 *= inv; a2 *= inv;
    float x0 = x[3 * node + 0], x1 = x[3 * node + 1], x2 = x[3 * node + 2];

    const float2* Wl = (const float2*)Wl0;
    const float2* Wr = (const float2*)Wr0;
    float2 v = ((const float2*)b0)[lane];
    float2 w;
    w = Wl[0 * 64 + lane]; v.x += a0 * w.x; v.y += a0 * w.y;
    w = Wl[1 * 64 + lane]; v.x += a1 * w.x; v.y += a1 * w.y;
    w = Wl[2 * 64 + lane]; v.x += a2 * w.x; v.y += a2 * w.y;
    w = Wr[0 * 64 + lane]; v.x += x0 * w.x; v.y += x0 * w.y;
    w = Wr[1 * 64 + lane]; v.x += x1 * w.x; v.y += x1 * w.y;
    w = Wr[2 * 64 + lane]; v.x += x2 * w.x; v.y += x2 * w.y;
    v.x = fmaxf(v.x, 0.0f); v.y = fmaxf(v.y, 0.0f);

    float s = v.x + v.y, q = v.x * v.x + v.y * v.y;
#pragma unroll
    for (int off = 32; off; off >>= 1) {
        s += __shfl_xor(s, off, 64);
        q += __shfl_xor(q, off, 64);
    }
    float mu = s * (1.0f / 128.0f);
    float var = q * (1.0f / 128.0f) - mu * mu;
    float rstd = rsqrtf(var + 1e-5f);
    float2 g = ((const float2*)ln_g)[lane];
    float2 bb = ((const float2*)ln_b)[lane];
    float o0 = (v.x - mu) * rstd * g.x + bb.x;
    float o1 = (v.y - mu) * rstd * g.y + bb.y;
    ((float2*)out)[(size_t)node * 64 + lane] = make_float2(o0, o1);
    unsigned u0 = bf16_rne(o0), u1 = bf16_rne(o1);
    h_bf[(size_t)node * 64 + lane] = u0 | (u1 << 16);
}

// Layer 1 fused: CSR mean-aggregate of h (bf16 gather) + out = relu(agg@Wl1 + h@Wr1 + b1).
// NT nodes per 256-thread block. Phase A: wave w gathers nodes {w,4+w,8+w,12+w} into LDS.
// Phase B: wave q computes nodes q*4..q*4+3, thread lane = j-pair, 4 nodes x float2 in regs
// so Wl1/Wr1 are fetched once per 16 nodes. In-place d_out write is safe: neighbors are
// read from the bf16 copy, only the node's OWN fp32 row is read (same block).
__global__ __launch_bounds__(256) void k_agg_l1(
        const float* __restrict__ Wl1, const float* __restrict__ Wr1,
        const float* __restrict__ b1,
        const int* __restrict__ counts, const int* __restrict__ row_start,
        const int* __restrict__ sorted_src, const unsigned* __restrict__ h_bf,
        float* __restrict__ out, int N) {
    __shared__ float2 ash[NT][128];  // .x = agg*inv, .y = own h
    int t = threadIdx.x;
    int wid = t >> 6, lane = t & 63;
    int node_base = blockIdx.x * NT;

#pragma unroll
    for (int i = 0; i < NT / 4; i++) {
        int nl = i * 4 + wid;
        int node = node_base + nl;
        float a0 = 0, a1 = 0, ox = 0, oy = 0;
        if (node < N) {
            int deg = counts[node], rs = row_start[node];
            float inv = 1.0f / fmaxf((float)deg, 1.0f);
            for (int k = 0; k < deg; k++) {
                int s = sorted_src[rs + k];
                unsigned u = h_bf[(size_t)s * 64 + lane];
                a0 += __uint_as_float(u << 16);
                a1 += __uint_as_float(u & 0xFFFF0000u);
            }
            a0 *= inv; a1 *= inv;
            float2 own = ((const float2*)out)[(size_t)node * 64 + lane];
            ox = own.x; oy = own.y;
        }
        ash[nl][2 * lane + 0] = make_float2(a0, ox);
        ash[nl][2 * lane + 1] = make_float2(a1, oy);
    }
    __syncthreads();

    int q = wid;
    int jp = lane;
    float2 bb = ((const float2*)b1)[jp];
    float2 acc0 = bb, acc1 = bb, acc2 = bb, acc3 = bb;
    const float2* Wl2 = (const float2*)Wl1;
    const float2* Wr2 = (const float2*)Wr1;
#pragma unroll 4
    for (int k = 0; k < 128; k++) {
        float2 wl = Wl2[k * 64 + jp];
        float2 wr = Wr2[k * 64 + jp];
        float2 a;
        a = ash[q * 4 + 0][k]; acc0.x += a.x * wl.x + a.y * wr.x; acc0.y += a.x * wl.y + a.y * wr.y;
        a = ash[q * 4 + 1][k]; acc1.x += a.x * wl.x + a.y * wr.x; acc1.y += a.x * wl.y + a.y * wr.y;
        a = ash[q * 4 + 2][k]; acc2.x += a.x * wl.x + a.y * wr.x; acc2.y += a.x * wl.y + a.y * wr.y;
        a = ash[q * 4 + 3][k]; acc3.x += a.x * wl.x + a.y * wr.x; acc3.y += a.x * wl.y + a.y * wr.y;
    }
    float2 r[4] = {acc0, acc1, acc2, acc3};
#pragma unroll
    for (int n = 0; n < 4; n++) {
        int node = node_base + q * 4 + n;
        if (node < N)
            ((float2*)out)[(size_t)node * 64 + jp] =
                make_float2(fmaxf(r[n].x, 0.0f), fmaxf(r[n].y, 0.0f));
    }
}

extern "C" void kernel_launch(void* const* d_in, const int* in_sizes, int n_in,
                              void* d_out, int out_size, void* d_ws, size_t ws_size,
                              hipStream_t stream) {
    const float* x    = (const float*)d_in[0];
    const int*   ei   = (const int*)d_in[1];
    const float* Wl0  = (const float*)d_in[2];
    const float* Wr0  = (const float*)d_in[3];
    const float* b0   = (const float*)d_in[4];
    const float* Wl1  = (const float*)d_in[5];
    const float* Wr1  = (const float*)d_in[6];
    const float* b1   = (const float*)d_in[7];
    const float* ln_g = (const float*)d_in[8];
    const float* ln_b = (const float*)d_in[9];
    float* out = (float*)d_out;

    const int N = in_sizes[0] / 3;
    const int E = in_sizes[1] / 2;
    const int* src = ei;
    const int* dst = ei + E;

    int* ws = (int*)d_ws;
    int* counts     = ws;
    int* cursor     = ws + (size_t)N;
    int* row_start  = ws + 2 * (size_t)N;
    int* blk_sums   = ws + 3 * (size_t)N;
    int* sorted_src = ws + 3 * (size_t)N + 128;
    unsigned* h_bf  = (unsigned*)(sorted_src + (size_t)E);

    const int nblk_scan = (N + 1023) / 1024;

    // zero counts + cursor only (800 KB)
    hipMemsetAsync(d_ws, 0, 2 * (size_t)N * sizeof(int), stream);

    k_hist<<<(E + 255) / 256, 256, 0, stream>>>(dst, counts, E);
    k_scan_blk<<<nblk_scan, 256, 0, stream>>>(counts, row_start, blk_sums, N);
    k_scan_top<<<1, 64, 0, stream>>>(blk_sums, nblk_scan);
    k_scan_add<<<nblk_scan, 256, 0, stream>>>(row_start, blk_sums, N);
    k_scatter<<<(E + 255) / 256, 256, 0, stream>>>(src, dst, row_start, cursor, sorted_src, E);
    k_l0<<<(N + 3) / 4, 256, 0, stream>>>(x, counts, row_start, sorted_src,
                                          Wl0, Wr0, b0, ln_g, ln_b, out, h_bf, N);
    k_agg_l1<<<(N + NT - 1) / NT, 256, 0, stream>>>(Wl1, Wr1, b1, counts, row_start,
                                                    sorted_src, h_bf, out, N);
}